// Round 1
// baseline (8786.685 us; speedup 1.0000x reference)
//
#include <hip/hip_runtime.h>
#include <math.h>

// Problem constants (from reference)
static constexpr int TT   = 1024;  // time
static constexpr int BB   = 64;    // batch
static constexpr int DHID = 256;   // hidden
static constexpr int NLAY = 8;     // layers
static constexpr int OSL  = 24;    // d_outputseqlen
static constexpr size_t HELEMS = (size_t)BB * DHID * TT;  // 16.7M elems = 64MB fp32

// ---------------------------------------------------------------------------
// Up projection: h[b][c][t] = sum_j [X_lag|X_cov][t,b,j] * up_w[j][c] + up_b[c]
// ---------------------------------------------------------------------------
__global__ __launch_bounds__(256) void up_kernel(
    const float* __restrict__ xlag, const float* __restrict__ xcov,
    const float* __restrict__ upw, const float* __restrict__ upb,
    float* __restrict__ h)
{
  const int b  = blockIdx.y;
  const int t0 = blockIdx.x * 16;
  __shared__ float xs[16][17];
  {
    const int tl = threadIdx.x >> 4;
    const int j  = threadIdx.x & 15;
    const size_t base = ((size_t)(t0 + tl) * BB + b) * 8;
    xs[tl][j] = (j < 8) ? xlag[base + j] : xcov[base + (j - 8)];
  }
  __syncthreads();
  const int c = threadIdx.x;
  float uw[16];
#pragma unroll
  for (int j = 0; j < 16; ++j) uw[j] = upw[j * DHID + c];
  const float bias = upb[c];
  float* hp = h + ((size_t)b * DHID + c) * TT + t0;
#pragma unroll
  for (int tl = 0; tl < 16; ++tl) {
    float acc = bias;
#pragma unroll
    for (int j = 0; j < 16; ++j) acc = fmaf(xs[tl][j], uw[j], acc);
    hp[tl] = acc;
  }
}

// ---------------------------------------------------------------------------
// Dilated causal conv (K=3) + bias + gate:
//   fg[o,t] = b[o] + sum_{c,k} w[o][c][k] * h[b][c][t-(2-k)*dil]
//   gated[c,t] = tanh(fg[c,t]) * sigmoid(fg[c+256,t])
// Block computes a 64(c) x 64(t) gated tile (needs fg rows c0..c0+63 and
// c0+256..c0+319). 256 threads as 16x16, 4x4 micro-tile per half.
// ---------------------------------------------------------------------------
__global__ __launch_bounds__(256) void conv_gate_kernel(
    const float* __restrict__ h, const float* __restrict__ w,   // [512][256][3] slice
    const float* __restrict__ cb,                               // [512]
    float* __restrict__ gated, const int dil)
{
  const int b  = blockIdx.z;
  const int c0 = blockIdx.y * 64;
  const int t0 = blockIdx.x * 64;
  const int tx = threadIdx.x & 15;   // t micro index
  const int ty = threadIdx.x >> 4;   // row micro index

  __shared__ float wf[16][68];  // [k-chunk][o] transposed, padded
  __shared__ float wg[16][68];
  __shared__ float hh[16][68];  // [k-chunk][t]

  float accf[4][4] = {{0.f}};
  float accg[4][4] = {{0.f}};
  const float* hb = h + (size_t)b * DHID * TT;

  const int oo   = threadIdx.x & 63;
  const int cb4  = (threadIdx.x >> 6) * 4;  // weight-load chunk base
  const int tt_l = threadIdx.x & 63;
  const int ccb  = threadIdx.x >> 6;        // h-load chunk base

  for (int tap = 0; tap < 3; ++tap) {
    const int shift = (2 - tap) * dil;
    for (int ck = 0; ck < 16; ++ck) {
      const int cc0 = ck * 16;
#pragma unroll
      for (int q = 0; q < 4; ++q) {
        const int cc = cb4 + q;
        wf[cc][oo] = w[(size_t)(c0 + oo)       * 768 + (cc0 + cc) * 3 + tap];
        wg[cc][oo] = w[(size_t)(c0 + 256 + oo) * 768 + (cc0 + cc) * 3 + tap];
      }
#pragma unroll
      for (int q = 0; q < 4; ++q) {
        const int cc = ccb + q * 4;
        const int tg = t0 + tt_l - shift;
        hh[cc][tt_l] = (tg >= 0) ? hb[(size_t)(cc0 + cc) * TT + tg] : 0.f;
      }
      __syncthreads();
#pragma unroll
      for (int k = 0; k < 16; ++k) {
        const float4 hq = *(const float4*)&hh[k][tx * 4];
        const float4 fq = *(const float4*)&wf[k][ty * 4];
        const float4 gq = *(const float4*)&wg[k][ty * 4];
        const float hv[4] = {hq.x, hq.y, hq.z, hq.w};
        const float fv[4] = {fq.x, fq.y, fq.z, fq.w};
        const float gv[4] = {gq.x, gq.y, gq.z, gq.w};
#pragma unroll
        for (int r = 0; r < 4; ++r)
#pragma unroll
          for (int q = 0; q < 4; ++q) {
            accf[r][q] = fmaf(fv[r], hv[q], accf[r][q]);
            accg[r][q] = fmaf(gv[r], hv[q], accg[r][q]);
          }
      }
      __syncthreads();
    }
  }

  float* gbase = gated + (size_t)b * DHID * TT;
#pragma unroll
  for (int r = 0; r < 4; ++r) {
    const int row = c0 + ty * 4 + r;
    const float bf = cb[row];
    const float bg = cb[row + 256];
    float tmp[4];
#pragma unroll
    for (int q = 0; q < 4; ++q) {
      const float f = accf[r][q] + bf;
      const float g = accg[r][q] + bg;
      tmp[q] = tanhf(f) * (1.f / (1.f + expf(-g)));
    }
    float4 o = {tmp[0], tmp[1], tmp[2], tmp[3]};
    *(float4*)&gbase[(size_t)row * TT + t0 + tx * 4] = o;
  }
}

// ---------------------------------------------------------------------------
// Skip matmul + residual update (in-place on h and skip):
//   hs[o,t] = sb[o] + sum_c skip_w[o][c] * gated[b][c][t]
//   h[b][c][t]    += hs[c,t]
//   skip[b][c][t] += hs[c+256,t]
// ---------------------------------------------------------------------------
__global__ __launch_bounds__(256) void skip_update_kernel(
    const float* __restrict__ gated, const float* __restrict__ sw,  // [512][256] slice
    const float* __restrict__ sb,                                   // [512]
    float* __restrict__ h, float* __restrict__ skip)
{
  const int b  = blockIdx.z;
  const int c0 = blockIdx.y * 64;
  const int t0 = blockIdx.x * 64;
  const int tx = threadIdx.x & 15;
  const int ty = threadIdx.x >> 4;

  __shared__ float wf[16][68];
  __shared__ float wg[16][68];
  __shared__ float gg[16][68];

  float accf[4][4] = {{0.f}};
  float accg[4][4] = {{0.f}};
  const float* gbase = gated + (size_t)b * DHID * TT;

  const int oo   = threadIdx.x & 63;
  const int cb4  = (threadIdx.x >> 6) * 4;
  const int tt_l = threadIdx.x & 63;
  const int ccb  = threadIdx.x >> 6;

  for (int ck = 0; ck < 16; ++ck) {
    const int cc0 = ck * 16;
#pragma unroll
    for (int q = 0; q < 4; ++q) {
      const int cc = cb4 + q;
      wf[cc][oo] = sw[(size_t)(c0 + oo)       * 256 + cc0 + cc];
      wg[cc][oo] = sw[(size_t)(c0 + 256 + oo) * 256 + cc0 + cc];
    }
#pragma unroll
    for (int q = 0; q < 4; ++q) {
      const int cc = ccb + q * 4;
      gg[cc][tt_l] = gbase[(size_t)(cc0 + cc) * TT + t0 + tt_l];
    }
    __syncthreads();
#pragma unroll
    for (int k = 0; k < 16; ++k) {
      const float4 hq = *(const float4*)&gg[k][tx * 4];
      const float4 fq = *(const float4*)&wf[k][ty * 4];
      const float4 gq = *(const float4*)&wg[k][ty * 4];
      const float hv[4] = {hq.x, hq.y, hq.z, hq.w};
      const float fv[4] = {fq.x, fq.y, fq.z, fq.w};
      const float gv[4] = {gq.x, gq.y, gq.z, gq.w};
#pragma unroll
      for (int r = 0; r < 4; ++r)
#pragma unroll
        for (int q = 0; q < 4; ++q) {
          accf[r][q] = fmaf(fv[r], hv[q], accf[r][q]);
          accg[r][q] = fmaf(gv[r], hv[q], accg[r][q]);
        }
    }
    __syncthreads();
  }

#pragma unroll
  for (int r = 0; r < 4; ++r) {
    const int row = c0 + ty * 4 + r;
    const float bf = sb[row];
    const float bg = sb[row + 256];
    float* hp = h    + ((size_t)b * DHID + row) * TT + t0 + tx * 4;
    float* sp = skip + ((size_t)b * DHID + row) * TT + t0 + tx * 4;
    float4 hq = *(float4*)hp;
    float4 sq = *(float4*)sp;
    hq.x += accf[r][0] + bf; hq.y += accf[r][1] + bf;
    hq.z += accf[r][2] + bf; hq.w += accf[r][3] + bf;
    sq.x += accg[r][0] + bg; sq.y += accg[r][1] + bg;
    sq.z += accg[r][2] + bg; sq.w += accg[r][3] + bg;
    *(float4*)hp = hq;
    *(float4*)sp = sq;
  }
}

// ---------------------------------------------------------------------------
// Head: for the last OSL timesteps only —
//   ff = relu(skip[b][:][t] @ fc_w + fc_b); loc = ff@loc_w+loc_b;
//   scale = softplus(ff@scale_w+scale_b)+1e-6. One block per (tt, b).
// ---------------------------------------------------------------------------
__global__ __launch_bounds__(256) void head_kernel(
    const float* __restrict__ skip,
    const float* __restrict__ fcw, const float* __restrict__ fcb,
    const float* __restrict__ locw, const float* __restrict__ locb,
    const float* __restrict__ scw, const float* __restrict__ scb,
    float* __restrict__ out)
{
  const int tt = blockIdx.x;           // 0..OSL-1
  const int b  = blockIdx.y;           // 0..BB-1
  const int t  = TT - OSL + tt;
  const int c  = threadIdx.x;          // 0..255
  __shared__ float xs[DHID];
  xs[c] = skip[((size_t)b * DHID + c) * TT + t];
  __syncthreads();
  float acc = fcb[c];
#pragma unroll 8
  for (int j = 0; j < DHID; ++j) acc = fmaf(xs[j], fcw[j * DHID + c], acc);
  const float ff = fmaxf(acc, 0.f);
  float pl = ff * locw[c];
  float ps = ff * scw[c];
#pragma unroll
  for (int off = 32; off > 0; off >>= 1) {
    pl += __shfl_down(pl, off);
    ps += __shfl_down(ps, off);
  }
  __shared__ float rl[4], rs[4];
  const int wid = threadIdx.x >> 6, lane = threadIdx.x & 63;
  if (lane == 0) { rl[wid] = pl; rs[wid] = ps; }
  __syncthreads();
  if (threadIdx.x == 0) {
    const float loc = rl[0] + rl[1] + rl[2] + rl[3] + locb[0];
    const float x   = rs[0] + rs[1] + rs[2] + rs[3] + scb[0];
    const float sp  = (x > 0.f) ? (x + log1pf(expf(-x))) : log1pf(expf(x));
    out[2 + tt * BB + b]            = loc;
    out[2 + OSL * BB + tt * BB + b] = sp + 1e-6f;
  }
}

// ---------------------------------------------------------------------------
// Loss: -mean(log_prob) over the OSL*BB tail; writes out[0], out[1].
// ---------------------------------------------------------------------------
__global__ __launch_bounds__(256) void loss_kernel(
    const float* __restrict__ y, float* __restrict__ out)
{
  float s = 0.f;
  for (int i = threadIdx.x; i < OSL * BB; i += 256) {
    const int tt = i >> 6, b = i & 63;
    const float loc = out[2 + i];
    const float sc  = out[2 + OSL * BB + i];
    const float yt  = y[(size_t)(TT - OSL + tt) * BB + b];
    const float z   = (yt - loc) / sc;
    s += -0.5f * z * z - logf(sc) - 0.9189385332046727f;  // 0.5*log(2*pi)
  }
#pragma unroll
  for (int off = 32; off > 0; off >>= 1) s += __shfl_down(s, off);
  __shared__ float r[4];
  if ((threadIdx.x & 63) == 0) r[threadIdx.x >> 6] = s;
  __syncthreads();
  if (threadIdx.x == 0) {
    const float loss = -(r[0] + r[1] + r[2] + r[3]) / (float)(OSL * BB);
    out[0] = loss;
    out[1] = loss;
  }
}

// ---------------------------------------------------------------------------
extern "C" void kernel_launch(void* const* d_in, const int* in_sizes, int n_in,
                              void* d_out, int out_size, void* d_ws, size_t ws_size,
                              hipStream_t stream) {
  (void)in_sizes; (void)n_in; (void)out_size; (void)ws_size;
  // dict order: 0 X_emb(int,unused) 1 X_cov 2 X_lag 3 y 4 domain(unused)
  // 5 up_w 6 up_b 7 conv_dil_w 8 conv_dil_b 9 skip_w 10 skip_b
  // 11 fc_w 12 fc_b 13 loc_w 14 loc_b 15 scale_w 16 scale_b 17 d_outputseqlen
  const float* X_cov  = (const float*)d_in[1];
  const float* X_lag  = (const float*)d_in[2];
  const float* y      = (const float*)d_in[3];
  const float* up_w   = (const float*)d_in[5];
  const float* up_b   = (const float*)d_in[6];
  const float* conv_w = (const float*)d_in[7];
  const float* conv_b = (const float*)d_in[8];
  const float* skip_w = (const float*)d_in[9];
  const float* skip_b = (const float*)d_in[10];
  const float* fc_w   = (const float*)d_in[11];
  const float* fc_b   = (const float*)d_in[12];
  const float* loc_w  = (const float*)d_in[13];
  const float* loc_b  = (const float*)d_in[14];
  const float* sc_w   = (const float*)d_in[15];
  const float* sc_b   = (const float*)d_in[16];

  float* h     = (float*)d_ws;          // [BB][DHID][TT]
  float* skip  = h + HELEMS;            // [BB][DHID][TT]
  float* gated = h + 2 * HELEMS;        // [BB][DHID][TT]

  hipMemsetAsync(skip, 0, HELEMS * sizeof(float), stream);

  up_kernel<<<dim3(TT / 16, BB), 256, 0, stream>>>(X_lag, X_cov, up_w, up_b, h);

  for (int i = 0; i < NLAY; ++i) {
    const int dil = 1 << i;
    conv_gate_kernel<<<dim3(TT / 64, DHID / 64, BB), 256, 0, stream>>>(
        h, conv_w + (size_t)i * 512 * 256 * 3, conv_b + i * 512, gated, dil);
    skip_update_kernel<<<dim3(TT / 64, DHID / 64, BB), 256, 0, stream>>>(
        gated, skip_w + (size_t)i * 512 * 256, skip_b + i * 512, h, skip);
  }

  head_kernel<<<dim3(OSL, BB), 256, 0, stream>>>(
      skip, fc_w, fc_b, loc_w, loc_b, sc_w, sc_b, (float*)d_out);
  loss_kernel<<<1, 256, 0, stream>>>(y, (float*)d_out);
}

// Round 2
// 993.303 us; speedup vs baseline: 8.8459x; 8.8459x over previous
//
#include <hip/hip_runtime.h>
#include <math.h>

static constexpr int TT = 1024, BB = 64, DHID = 256, NLAY = 8, OSL = 24;
static constexpr size_t HELEMS = (size_t)BB * DHID * TT;   // 16.78M

typedef __attribute__((ext_vector_type(8))) short short8;  // 8 bf16 (4 VGPRs)
typedef __attribute__((ext_vector_type(4))) float f32x4;
typedef unsigned short u16;
typedef unsigned int u32;

__device__ __forceinline__ u16 f2bf(float x) {
  u32 u = __float_as_uint(x);
  return (u16)((u + 0x7fffu + ((u >> 16) & 1u)) >> 16);   // RNE
}

__device__ __forceinline__ void gll16(const u16* g, u16* l) {
  // async global->LDS, 16B/lane; LDS dest = wave-uniform base + lane*16
  __builtin_amdgcn_global_load_lds((const __attribute__((address_space(1))) void*)g,
                                   (__attribute__((address_space(3))) void*)l, 16, 0, 0);
}

// ---------------------------------------------------------------------------
// Weight prep: conv_w [l][o][c][k] f32 -> wT [l][tap][o][c] bf16;
//              skip_w [l][o][c] f32 -> swT same layout bf16.
// ---------------------------------------------------------------------------
__global__ __launch_bounds__(256) void wprep(
    const float* __restrict__ cw, const float* __restrict__ sw,
    u16* __restrict__ wT, u16* __restrict__ swT)
{
  const int stride = gridDim.x * 256;
  for (int idx = blockIdx.x * 256 + threadIdx.x; idx < NLAY * 3 * 512 * 256; idx += stride) {
    const int c = idx & 255;
    const int o = (idx >> 8) & 511;
    const int lt = idx >> 17;            // l*3 + tap
    const int tap = lt % 3, l = lt / 3;
    wT[idx] = f2bf(cw[((size_t)(l * 512 + o) * 256 + c) * 3 + tap]);
  }
  for (int idx = blockIdx.x * 256 + threadIdx.x; idx < NLAY * 512 * 256; idx += stride)
    swT[idx] = f2bf(sw[idx]);
}

// ---------------------------------------------------------------------------
// Up projection -> h_f32 and h_bf16 (full t range; it's cheap).
// ---------------------------------------------------------------------------
__global__ __launch_bounds__(256) void up_kernel(
    const float* __restrict__ xlag, const float* __restrict__ xcov,
    const float* __restrict__ upw, const float* __restrict__ upb,
    float* __restrict__ h, u16* __restrict__ hbf)
{
  const int b  = blockIdx.y;
  const int t0 = blockIdx.x * 16;
  __shared__ float xs[16][17];
  {
    const int tl = threadIdx.x >> 4;
    const int j  = threadIdx.x & 15;
    const size_t base = ((size_t)(t0 + tl) * BB + b) * 8;
    xs[tl][j] = (j < 8) ? xlag[base + j] : xcov[base + (j - 8)];
  }
  __syncthreads();
  const int c = threadIdx.x;
  float uw[16];
#pragma unroll
  for (int j = 0; j < 16; ++j) uw[j] = upw[j * DHID + c];
  const float bias = upb[c];
  float* hp  = h   + ((size_t)b * DHID + c) * TT + t0;
  u16*   hbp = hbf + ((size_t)b * DHID + c) * TT + t0;
#pragma unroll
  for (int tl = 0; tl < 16; ++tl) {
    float acc = bias;
#pragma unroll
    for (int j = 0; j < 16; ++j) acc = fmaf(xs[tl][j], uw[j], acc);
    hp[tl]  = acc;
    hbp[tl] = f2bf(acc);
  }
}

// ---------------------------------------------------------------------------
// MFMA conv+gate: fg[o,t] = sum_{c,tap} wT[tap][o][c]*h[c][t-(2-tap)*dil]
// Block = one (batch, 64-t tile), all 512 conv rows; 8 waves, wave w owns
// f-rows [32w,32w+32) and g-rows [256+32w, ...). gated bf16 -> global.
// ---------------------------------------------------------------------------
__global__ __launch_bounds__(512) void conv_gate_mfma(
    const u16* __restrict__ hbf, const u16* __restrict__ wT,
    const float* __restrict__ cb, u16* __restrict__ gated,
    const int dil, const int tile0)
{
  __shared__ u16 As[512 * 32];   // [o][c-chunk 32]
  __shared__ u16 Bs[64 * 32];    // [t-local][c-chunk 32] (transposed, shift baked in)
  const int b   = blockIdx.y;
  const int t0  = (tile0 + blockIdx.x) * 64;
  const int tid = threadIdx.x;
  const int w = tid >> 6, lane = tid & 63;
  const int l16 = lane & 15, quad = lane >> 4;
  const u16* hb = hbf + (size_t)b * DHID * TT;

  f32x4 accf[2][4], accg[2][4];
  const f32x4 zero = {0.f, 0.f, 0.f, 0.f};
#pragma unroll
  for (int i = 0; i < 2; ++i)
#pragma unroll
    for (int j = 0; j < 4; ++j) { accf[i][j] = zero; accg[i][j] = zero; }

  for (int tap = 0; tap < 3; ++tap) {
    const int sh = (2 - tap) * dil;        // t0-sh >= 0 by P-table construction
    const u16* wtap = wT + (size_t)tap * 512 * 256;
    for (int kc = 0; kc < 8; ++kc) {
      const int c0 = kc * 32;
#pragma unroll
      for (int q = 0; q < 4; ++q) {        // stage A: 512x32 bf16 = 32KB
        const int lin = q * 512 + tid;     // 16B chunk id
        gll16(wtap + (size_t)(lin >> 2) * 256 + c0 + (lin & 3) * 8,
              As + (size_t)(q * 512 + (tid & ~63)) * 8);
      }
      {                                    // stage B transposed: h[c][t0-sh + tl]
        const int c = tid >> 4, tq = tid & 15;
        const u16* hrow = hb + (size_t)(c0 + c) * TT + (t0 - sh) + tq * 4;
#pragma unroll
        for (int uu = 0; uu < 4; ++uu)
          Bs[(tq * 4 + uu) * 32 + c] = hrow[uu];
      }
      __syncthreads();
      short8 bfr[4];
#pragma unroll
      for (int nt = 0; nt < 4; ++nt)
        bfr[nt] = *(const short8*)&Bs[(nt * 16 + l16) * 32 + quad * 8];
#pragma unroll
      for (int mh = 0; mh < 2; ++mh) {
        const int of = 32 * w + mh * 16 + l16;
        short8 af = *(const short8*)&As[(size_t)of * 32 + quad * 8];
        short8 ag = *(const short8*)&As[(size_t)(256 + of) * 32 + quad * 8];
#pragma unroll
        for (int nt = 0; nt < 4; ++nt) {
          accf[mh][nt] = __builtin_amdgcn_mfma_f32_16x16x32_bf16(af, bfr[nt], accf[mh][nt], 0, 0, 0);
          accg[mh][nt] = __builtin_amdgcn_mfma_f32_16x16x32_bf16(ag, bfr[nt], accg[mh][nt], 0, 0, 0);
        }
      }
      __syncthreads();
    }
  }
  // epilogue: bias + tanh(f)*sigmoid(g) -> gated bf16
  u16* gb = gated + (size_t)b * DHID * TT;
#pragma unroll
  for (int mh = 0; mh < 2; ++mh) {
#pragma unroll
    for (int r = 0; r < 4; ++r) {
      const int c = 32 * w + mh * 16 + quad * 4 + r;
      const float bf_ = cb[c], bg_ = cb[256 + c];
#pragma unroll
      for (int nt = 0; nt < 4; ++nt) {
        const float f = accf[mh][nt][r] + bf_;
        const float g = accg[mh][nt][r] + bg_;
        const float th = 2.f / (1.f + __expf(-2.f * f)) - 1.f;
        const float sg = 1.f / (1.f + __expf(-g));
        gb[(size_t)c * TT + t0 + nt * 16 + l16] = f2bf(th * sg);
      }
    }
  }
}

// ---------------------------------------------------------------------------
// MFMA skip GEMM + residual: hs[o,t] = sum_c swT[o][c]*gated[c][t].
// h-half (o<256) on every tile: h_f32 += hs, h_bf16 mirror.
// skip-half (o>=256) only on tile 15 -> skip_f32 [BB][256][64] +=.
// ---------------------------------------------------------------------------
__global__ __launch_bounds__(512) void skip_mfma(
    const u16* __restrict__ gated, const u16* __restrict__ swT,
    const float* __restrict__ sb, float* __restrict__ hf,
    u16* __restrict__ hbf, float* __restrict__ skip, const int tile0)
{
  __shared__ u16 As[512 * 32];
  __shared__ u16 Bs[64 * 32];
  const int b    = blockIdx.y;
  const int tile = tile0 + blockIdx.x;
  const int t0   = tile * 64;
  const bool last = (tile == 15);
  const int tid = threadIdx.x, w = tid >> 6, lane = tid & 63;
  const int l16 = lane & 15, quad = lane >> 4;
  const u16* gbp = gated + (size_t)b * DHID * TT;

  f32x4 acch[2][4], accs[2][4];
  const f32x4 zero = {0.f, 0.f, 0.f, 0.f};
#pragma unroll
  for (int i = 0; i < 2; ++i)
#pragma unroll
    for (int j = 0; j < 4; ++j) { acch[i][j] = zero; accs[i][j] = zero; }

  const int nq = last ? 4 : 2;  // stage 512 rows only when skip-half needed
  for (int kc = 0; kc < 8; ++kc) {
    const int c0 = kc * 32;
    for (int q = 0; q < nq; ++q) {
      const int lin = q * 512 + tid;
      gll16(swT + (size_t)(lin >> 2) * 256 + c0 + (lin & 3) * 8,
            As + (size_t)(q * 512 + (tid & ~63)) * 8);
    }
    {
      const int c = tid >> 4, tq = tid & 15;
      const u16* grow = gbp + (size_t)(c0 + c) * TT + t0 + tq * 4;
#pragma unroll
      for (int uu = 0; uu < 4; ++uu)
        Bs[(tq * 4 + uu) * 32 + c] = grow[uu];
    }
    __syncthreads();
    short8 bfr[4];
#pragma unroll
    for (int nt = 0; nt < 4; ++nt)
      bfr[nt] = *(const short8*)&Bs[(nt * 16 + l16) * 32 + quad * 8];
#pragma unroll
    for (int mh = 0; mh < 2; ++mh) {
      const int of = 32 * w + mh * 16 + l16;
      short8 a = *(const short8*)&As[(size_t)of * 32 + quad * 8];
#pragma unroll
      for (int nt = 0; nt < 4; ++nt)
        acch[mh][nt] = __builtin_amdgcn_mfma_f32_16x16x32_bf16(a, bfr[nt], acch[mh][nt], 0, 0, 0);
    }
    if (last) {
#pragma unroll
      for (int mh = 0; mh < 2; ++mh) {
        const int of = 32 * w + mh * 16 + l16;
        short8 a = *(const short8*)&As[(size_t)(256 + of) * 32 + quad * 8];
#pragma unroll
        for (int nt = 0; nt < 4; ++nt)
          accs[mh][nt] = __builtin_amdgcn_mfma_f32_16x16x32_bf16(a, bfr[nt], accs[mh][nt], 0, 0, 0);
      }
    }
    __syncthreads();
  }
  // epilogue: h residual update
#pragma unroll
  for (int mh = 0; mh < 2; ++mh) {
#pragma unroll
    for (int r = 0; r < 4; ++r) {
      const int c = 32 * w + mh * 16 + quad * 4 + r;
      const float bias = sb[c];
#pragma unroll
      for (int nt = 0; nt < 4; ++nt) {
        const size_t idx = ((size_t)b * DHID + c) * TT + t0 + nt * 16 + l16;
        const float v = hf[idx] + acch[mh][nt][r] + bias;
        hf[idx] = v;
        hbf[idx] = f2bf(v);
      }
    }
  }
  if (last) {
#pragma unroll
    for (int mh = 0; mh < 2; ++mh) {
#pragma unroll
      for (int r = 0; r < 4; ++r) {
        const int c = 32 * w + mh * 16 + quad * 4 + r;
        const float bias = sb[256 + c];
#pragma unroll
        for (int nt = 0; nt < 4; ++nt) {
          const size_t sidx = ((size_t)b * DHID + c) * 64 + nt * 16 + l16;
          skip[sidx] += accs[mh][nt][r] + bias;
        }
      }
    }
  }
}

// ---------------------------------------------------------------------------
// Head over last OSL timesteps; skip layout [BB][256][64] (t 960..1023).
// ---------------------------------------------------------------------------
__global__ __launch_bounds__(256) void head_kernel(
    const float* __restrict__ skip,
    const float* __restrict__ fcw, const float* __restrict__ fcb,
    const float* __restrict__ locw, const float* __restrict__ locb,
    const float* __restrict__ scw, const float* __restrict__ scb,
    float* __restrict__ out)
{
  const int tt = blockIdx.x;   // 0..OSL-1
  const int b  = blockIdx.y;
  const int tl = 40 + tt;      // (TT-OSL+tt) - 960
  const int c  = threadIdx.x;
  __shared__ float xs[DHID];
  xs[c] = skip[((size_t)b * DHID + c) * 64 + tl];
  __syncthreads();
  float acc = fcb[c];
#pragma unroll 8
  for (int j = 0; j < DHID; ++j) acc = fmaf(xs[j], fcw[j * DHID + c], acc);
  const float ff = fmaxf(acc, 0.f);
  float pl = ff * locw[c];
  float ps = ff * scw[c];
#pragma unroll
  for (int off = 32; off > 0; off >>= 1) {
    pl += __shfl_down(pl, off);
    ps += __shfl_down(ps, off);
  }
  __shared__ float rl[4], rs[4];
  const int wid = threadIdx.x >> 6, lane = threadIdx.x & 63;
  if (lane == 0) { rl[wid] = pl; rs[wid] = ps; }
  __syncthreads();
  if (threadIdx.x == 0) {
    const float loc = rl[0] + rl[1] + rl[2] + rl[3] + locb[0];
    const float x   = rs[0] + rs[1] + rs[2] + rs[3] + scb[0];
    const float sp  = (x > 0.f) ? (x + log1pf(expf(-x))) : log1pf(expf(x));
    out[2 + tt * BB + b]            = loc;
    out[2 + OSL * BB + tt * BB + b] = sp + 1e-6f;
  }
}

__global__ __launch_bounds__(256) void loss_kernel(
    const float* __restrict__ y, float* __restrict__ out)
{
  float s = 0.f;
  for (int i = threadIdx.x; i < OSL * BB; i += 256) {
    const int tt = i >> 6, b = i & 63;
    const float loc = out[2 + i];
    const float sc  = out[2 + OSL * BB + i];
    const float yt  = y[(size_t)(TT - OSL + tt) * BB + b];
    const float z   = (yt - loc) / sc;
    s += -0.5f * z * z - logf(sc) - 0.9189385332046727f;
  }
#pragma unroll
  for (int off = 32; off > 0; off >>= 1) s += __shfl_down(s, off);
  __shared__ float r[4];
  if ((threadIdx.x & 63) == 0) r[threadIdx.x >> 6] = s;
  __syncthreads();
  if (threadIdx.x == 0) {
    const float loss = -(r[0] + r[1] + r[2] + r[3]) / (float)(OSL * BB);
    out[0] = loss;
    out[1] = loss;
  }
}

// ---------------------------------------------------------------------------
extern "C" void kernel_launch(void* const* d_in, const int* in_sizes, int n_in,
                              void* d_out, int out_size, void* d_ws, size_t ws_size,
                              hipStream_t stream) {
  (void)in_sizes; (void)n_in; (void)out_size; (void)ws_size;
  const float* X_cov  = (const float*)d_in[1];
  const float* X_lag  = (const float*)d_in[2];
  const float* y      = (const float*)d_in[3];
  const float* up_w   = (const float*)d_in[5];
  const float* up_b   = (const float*)d_in[6];
  const float* conv_w = (const float*)d_in[7];
  const float* conv_b = (const float*)d_in[8];
  const float* skip_w = (const float*)d_in[9];
  const float* skip_b = (const float*)d_in[10];
  const float* fc_w   = (const float*)d_in[11];
  const float* fc_b   = (const float*)d_in[12];
  const float* loc_w  = (const float*)d_in[13];
  const float* loc_b  = (const float*)d_in[14];
  const float* sc_w   = (const float*)d_in[15];
  const float* sc_b   = (const float*)d_in[16];

  // workspace layout (bytes)
  float* h      = (float*)d_ws;                               // 64 MB
  float* skipf  = (float*)((char*)d_ws + 67108864);           // 4 MB [BB][256][64]
  u16*   hbf    = (u16*)  ((char*)d_ws + 71303168);           // 32 MB
  u16*   gatedb = (u16*)  ((char*)d_ws + 104857600);          // 32 MB
  u16*   wT     = (u16*)  ((char*)d_ws + 138412032);          // 6 MB
  u16*   swT    = (u16*)  ((char*)d_ws + 144703488);          // 2 MB

  wprep<<<2048, 256, 0, stream>>>(conv_w, skip_w, wT, swT);
  hipMemsetAsync(skipf, 0, (size_t)BB * DHID * 64 * sizeof(float), stream);
  up_kernel<<<dim3(TT / 16, BB), 256, 0, stream>>>(X_lag, X_cov, up_w, up_b, h, hbf);

  // minimal t-tiles per layer so that the final 24 timesteps are exact:
  // 64*P(i) - 2^(i+1) >= 64*P(i-1) holds for all i (receptive-field recurrence)
  static const int Ptab[NLAY] = {4, 5, 6, 7, 8, 9, 11, 15};
  for (int i = 0; i < NLAY; ++i) {
    const int ntiles = 16 - Ptab[i];
    conv_gate_mfma<<<dim3(ntiles, BB), 512, 0, stream>>>(
        hbf, wT + (size_t)i * 3 * 512 * 256, conv_b + i * 512, gatedb, 1 << i, Ptab[i]);
    skip_mfma<<<dim3(ntiles, BB), 512, 0, stream>>>(
        gatedb, swT + (size_t)i * 512 * 256, skip_b + i * 512, h, hbf, skipf, Ptab[i]);
  }

  head_kernel<<<dim3(OSL, BB), 256, 0, stream>>>(
      skipf, fc_w, fc_b, loc_w, loc_b, sc_w, sc_b, (float*)d_out);
  loss_kernel<<<1, 256, 0, stream>>>(y, (float*)d_out);
}

// Round 3
// 734.286 us; speedup vs baseline: 11.9663x; 1.3527x over previous
//
#include <hip/hip_runtime.h>
#include <math.h>

static constexpr int TT = 1024, BB = 64, DHID = 256, NLAY = 8, OSL = 24;

typedef __attribute__((ext_vector_type(8))) short short8;   // 8 bf16
typedef __attribute__((ext_vector_type(4))) float f32x4;
typedef unsigned short u16;
typedef __attribute__((ext_vector_type(4))) unsigned short u16x4;
typedef unsigned int u32;

__device__ __forceinline__ u16 f2bf(float x) {
  u32 u = __float_as_uint(x);
  return (u16)((u + 0x7fffu + ((u >> 16) & 1u)) >> 16);   // RNE
}

__device__ __forceinline__ void gll16(const u16* g, u16* l) {
  // async global->LDS, 16B/lane; LDS dest = wave-uniform base + lane*16
  __builtin_amdgcn_global_load_lds((const __attribute__((address_space(1))) void*)g,
                                   (__attribute__((address_space(3))) void*)l, 16, 0, 0);
}

// ---------------------------------------------------------------------------
// Weight prep: conv_w [l][o][c][k] f32 -> wT [l][tap][o][c] bf16;
//              skip_w [l][o][c] f32 -> swT bf16 (same layout).
// ---------------------------------------------------------------------------
__global__ __launch_bounds__(256) void wprep(
    const float* __restrict__ cw, const float* __restrict__ sw,
    u16* __restrict__ wT, u16* __restrict__ swT)
{
  const int stride = gridDim.x * 256;
  for (int idx = blockIdx.x * 256 + threadIdx.x; idx < NLAY * 3 * 512 * 256; idx += stride) {
    const int c = idx & 255;
    const int o = (idx >> 8) & 511;
    const int lt = idx >> 17;
    const int tap = lt % 3, l = lt / 3;
    wT[idx] = f2bf(cw[((size_t)(l * 512 + o) * 256 + c) * 3 + tap]);
  }
  for (int idx = blockIdx.x * 256 + threadIdx.x; idx < NLAY * 512 * 256; idx += stride)
    swT[idx] = f2bf(sw[idx]);
}

// ---------------------------------------------------------------------------
// Up projection -> h_f32 [b][t][c] and hb0 bf16 mirror (same layout).
// ---------------------------------------------------------------------------
__global__ __launch_bounds__(256) void up_kernel(
    const float* __restrict__ xlag, const float* __restrict__ xcov,
    const float* __restrict__ upw, const float* __restrict__ upb,
    float* __restrict__ h, u16* __restrict__ hb0)
{
  const int b  = blockIdx.y;
  const int t0 = blockIdx.x * 16;
  __shared__ float xs[16][17];
  {
    const int tl = threadIdx.x >> 4;
    const int j  = threadIdx.x & 15;
    const size_t base = ((size_t)(t0 + tl) * BB + b) * 8;
    xs[tl][j] = (j < 8) ? xlag[base + j] : xcov[base + (j - 8)];
  }
  __syncthreads();
  const int c = threadIdx.x;
  float uw[16];
#pragma unroll
  for (int j = 0; j < 16; ++j) uw[j] = upw[j * DHID + c];
  const float bias = upb[c];
#pragma unroll
  for (int tl = 0; tl < 16; ++tl) {
    float acc = bias;
#pragma unroll
    for (int j = 0; j < 16; ++j) acc = fmaf(xs[tl][j], uw[j], acc);
    const size_t idx = ((size_t)b * TT + t0 + tl) * DHID + c;
    h[idx]   = acc;
    hb0[idx] = f2bf(acc);
  }
}

// ---------------------------------------------------------------------------
// Fused layer: conv(K=3,dil)+gate -> gated in LDS -> skip GEMM -> residual.
// Block = (t-tile 64, batch). 8 waves; wave w owns conv rows {32w..32w+31}
// (f) and {256+32w..} (g), then skip rows likewise.
// h bf16 ping-pong: reads hbin, writes hbout (race-free); hf f32 master is
// RMW'd only at the block's own tile.
// ---------------------------------------------------------------------------
__global__ __launch_bounds__(512, 4) void layer_fused(
    const u16* __restrict__ hbin, const u16* __restrict__ wT,
    const float* __restrict__ cb, const u16* __restrict__ swT,
    const float* __restrict__ sb, float* __restrict__ hf,
    u16* __restrict__ hbout, float* __restrict__ skipf,
    const int dil, const int tile0)
{
  __shared__ u16 As[512 * 32];     // weights [o][32c], rows 64B
  __shared__ u16 Bs[64 * 32];      // activations [t][32c], rows 64B
  __shared__ u16 gLDS[64 * 264];   // gated [t][c], padded stride 264 u16

  const int b    = blockIdx.y;
  const int tile = tile0 + blockIdx.x;
  const int t0   = tile * 64;
  const bool last = (tile == 15);
  const int tid = threadIdx.x, w = tid >> 6, lane = tid & 63;
  const int l16 = lane & 15, quad = lane >> 4;
  const u16* hb = hbin + (size_t)b * TT * DHID;

  f32x4 acc[4][4];
  const f32x4 zero = {0.f, 0.f, 0.f, 0.f};
#pragma unroll
  for (int m = 0; m < 4; ++m)
#pragma unroll
    for (int n = 0; n < 4; ++n) acc[m][n] = zero;

  // ---------------- phase 1: conv + gate ----------------
  for (int tap = 0; tap < 3; ++tap) {
    const int sh = (2 - tap) * dil;               // t0-sh >= 0 by P-table
    const u16* wtap = wT + (size_t)tap * 512 * 256;
    for (int kc = 0; kc < 8; ++kc) {
      const int c0 = kc * 32;
#pragma unroll
      for (int q = 0; q < 4; ++q) {               // A: 512x32 = 32KB
        const int lin = q * 512 + tid;
        gll16(wtap + (size_t)(lin >> 2) * 256 + c0 + (lin & 3) * 8,
              As + (size_t)(q * 512 + (tid & ~63)) * 8);
      }
      if (w < 4) {                                // B: 64x32 = 4KB, [t][c] direct
        const int tl = 16 * w + (lane >> 2);
        gll16(hb + (size_t)(t0 - sh + tl) * 256 + c0 + (lane & 3) * 8,
              Bs + w * 512);
      }
      __syncthreads();
      short8 bfr[4], afr[4];
#pragma unroll
      for (int nt = 0; nt < 4; ++nt)
        bfr[nt] = *(const short8*)&Bs[(nt * 16 + l16) * 32 + quad * 8];
#pragma unroll
      for (int m = 0; m < 4; ++m) {
        const int o = ((m & 2) ? 256 : 0) + 32 * w + (m & 1) * 16 + l16;
        afr[m] = *(const short8*)&As[(size_t)o * 32 + quad * 8];
      }
#pragma unroll
      for (int m = 0; m < 4; ++m)
#pragma unroll
        for (int nt = 0; nt < 4; ++nt)
          acc[m][nt] = __builtin_amdgcn_mfma_f32_16x16x32_bf16(afr[m], bfr[nt], acc[m][nt], 0, 0, 0);
      __syncthreads();
    }
  }

  // gate -> gLDS [t][c] (8B stores, ~2-way conflict = free)
#pragma unroll
  for (int mf = 0; mf < 2; ++mf) {
#pragma unroll
    for (int nt = 0; nt < 4; ++nt) {
      u16x4 pk;
#pragma unroll
      for (int r = 0; r < 4; ++r) {
        const int c = 32 * w + mf * 16 + quad * 4 + r;
        const float f = acc[mf][nt][r] + cb[c];
        const float g = acc[mf + 2][nt][r] + cb[256 + c];
        const float th = 2.f / (1.f + __expf(-2.f * f)) - 1.f;
        const float sg = 1.f / (1.f + __expf(-g));
        pk[r] = f2bf(th * sg);
      }
      *(u16x4*)&gLDS[(size_t)(nt * 16 + l16) * 264 + 32 * w + mf * 16 + quad * 4] = pk;
    }
  }
  __syncthreads();

  // ---------------- phase 2: skip GEMM ----------------
#pragma unroll
  for (int m = 0; m < 4; ++m)
#pragma unroll
    for (int n = 0; n < 4; ++n) acc[m][n] = zero;

  const int nq = last ? 4 : 2;        // stage rows 512 only when skip-half needed
  for (int kc = 0; kc < 8; ++kc) {
    const int c0 = kc * 32;
    for (int q = 0; q < nq; ++q) {
      const int lin = q * 512 + tid;
      gll16(swT + (size_t)(lin >> 2) * 256 + c0 + (lin & 3) * 8,
            As + (size_t)(q * 512 + (tid & ~63)) * 8);
    }
    __syncthreads();
    short8 bfr[4];
#pragma unroll
    for (int nt = 0; nt < 4; ++nt)
      bfr[nt] = *(const short8*)&gLDS[(size_t)(nt * 16 + l16) * 264 + c0 + quad * 8];
#pragma unroll
    for (int m = 0; m < 2; ++m) {
      const int o = 32 * w + m * 16 + l16;
      short8 a = *(const short8*)&As[(size_t)o * 32 + quad * 8];
#pragma unroll
      for (int nt = 0; nt < 4; ++nt)
        acc[m][nt] = __builtin_amdgcn_mfma_f32_16x16x32_bf16(a, bfr[nt], acc[m][nt], 0, 0, 0);
    }
    if (last) {
#pragma unroll
      for (int m = 2; m < 4; ++m) {
        const int o = 256 + 32 * w + (m & 1) * 16 + l16;
        short8 a = *(const short8*)&As[(size_t)o * 32 + quad * 8];
#pragma unroll
        for (int nt = 0; nt < 4; ++nt)
          acc[m][nt] = __builtin_amdgcn_mfma_f32_16x16x32_bf16(a, bfr[nt], acc[m][nt], 0, 0, 0);
      }
    }
    __syncthreads();
  }

  // epilogue: h residual RMW (own tile only) + bf16 mirror to hbout
#pragma unroll
  for (int mh = 0; mh < 2; ++mh) {
#pragma unroll
    for (int nt = 0; nt < 4; ++nt) {
      const int t  = t0 + nt * 16 + l16;
      const int c4 = 32 * w + mh * 16 + quad * 4;
      const size_t idx = ((size_t)b * TT + t) * DHID + c4;
      f32x4 hv = *(f32x4*)&hf[idx];
      u16x4 pk;
#pragma unroll
      for (int r = 0; r < 4; ++r) {
        const float v = hv[r] + acc[mh][nt][r] + sb[c4 + r];
        hv[r] = v;
        pk[r] = f2bf(v);
      }
      *(f32x4*)&hf[idx] = hv;
      *(u16x4*)&hbout[idx] = pk;
    }
  }
  if (last) {
#pragma unroll
    for (int mh = 0; mh < 2; ++mh) {
#pragma unroll
      for (int nt = 0; nt < 4; ++nt) {
        const int tl = nt * 16 + l16;
        const int c4 = 32 * w + mh * 16 + quad * 4;
        const size_t idx = ((size_t)b * 64 + tl) * DHID + c4;
        f32x4 sv = *(f32x4*)&skipf[idx];
#pragma unroll
        for (int r = 0; r < 4; ++r)
          sv[r] += acc[mh + 2][nt][r] + sb[256 + c4 + r];
        *(f32x4*)&skipf[idx] = sv;
      }
    }
  }
}

// ---------------------------------------------------------------------------
// Head over last OSL timesteps; skipf layout [b][64t][256c].
// ---------------------------------------------------------------------------
__global__ __launch_bounds__(256) void head_kernel(
    const float* __restrict__ skipf,
    const float* __restrict__ fcw, const float* __restrict__ fcb,
    const float* __restrict__ locw, const float* __restrict__ locb,
    const float* __restrict__ scw, const float* __restrict__ scb,
    float* __restrict__ out)
{
  const int tt = blockIdx.x;
  const int b  = blockIdx.y;
  const int tl = 40 + tt;
  const int c  = threadIdx.x;
  __shared__ float xs[DHID];
  xs[c] = skipf[((size_t)b * 64 + tl) * DHID + c];
  __syncthreads();
  float acc = fcb[c];
#pragma unroll 8
  for (int j = 0; j < DHID; ++j) acc = fmaf(xs[j], fcw[j * DHID + c], acc);
  const float ff = fmaxf(acc, 0.f);
  float pl = ff * locw[c];
  float ps = ff * scw[c];
#pragma unroll
  for (int off = 32; off > 0; off >>= 1) {
    pl += __shfl_down(pl, off);
    ps += __shfl_down(ps, off);
  }
  __shared__ float rl[4], rs[4];
  const int wid = threadIdx.x >> 6, lane = threadIdx.x & 63;
  if (lane == 0) { rl[wid] = pl; rs[wid] = ps; }
  __syncthreads();
  if (threadIdx.x == 0) {
    const float loc = rl[0] + rl[1] + rl[2] + rl[3] + locb[0];
    const float x   = rs[0] + rs[1] + rs[2] + rs[3] + scb[0];
    const float sp  = (x > 0.f) ? (x + log1pf(expf(-x))) : log1pf(expf(x));
    out[2 + tt * BB + b]            = loc;
    out[2 + OSL * BB + tt * BB + b] = sp + 1e-6f;
  }
}

__global__ __launch_bounds__(256) void loss_kernel(
    const float* __restrict__ y, float* __restrict__ out)
{
  float s = 0.f;
  for (int i = threadIdx.x; i < OSL * BB; i += 256) {
    const int tt = i >> 6, b = i & 63;
    const float loc = out[2 + i];
    const float sc  = out[2 + OSL * BB + i];
    const float yt  = y[(size_t)(TT - OSL + tt) * BB + b];
    const float z   = (yt - loc) / sc;
    s += -0.5f * z * z - logf(sc) - 0.9189385332046727f;
  }
#pragma unroll
  for (int off = 32; off > 0; off >>= 1) s += __shfl_down(s, off);
  __shared__ float r[4];
  if ((threadIdx.x & 63) == 0) r[threadIdx.x >> 6] = s;
  __syncthreads();
  if (threadIdx.x == 0) {
    const float loss = -(r[0] + r[1] + r[2] + r[3]) / (float)(OSL * BB);
    out[0] = loss;
    out[1] = loss;
  }
}

// ---------------------------------------------------------------------------
extern "C" void kernel_launch(void* const* d_in, const int* in_sizes, int n_in,
                              void* d_out, int out_size, void* d_ws, size_t ws_size,
                              hipStream_t stream) {
  (void)in_sizes; (void)n_in; (void)out_size; (void)ws_size;
  const float* X_cov  = (const float*)d_in[1];
  const float* X_lag  = (const float*)d_in[2];
  const float* y      = (const float*)d_in[3];
  const float* up_w   = (const float*)d_in[5];
  const float* up_b   = (const float*)d_in[6];
  const float* conv_w = (const float*)d_in[7];
  const float* conv_b = (const float*)d_in[8];
  const float* skip_w = (const float*)d_in[9];
  const float* skip_b = (const float*)d_in[10];
  const float* fc_w   = (const float*)d_in[11];
  const float* fc_b   = (const float*)d_in[12];
  const float* loc_w  = (const float*)d_in[13];
  const float* loc_b  = (const float*)d_in[14];
  const float* sc_w   = (const float*)d_in[15];
  const float* sc_b   = (const float*)d_in[16];

  // workspace layout (bytes), total 140MB
  float* hf    = (float*)d_ws;                           // 64MB  [b][t][c] f32
  u16*   hb0   = (u16*)  ((char*)d_ws + 67108864);       // 32MB  bf16 ping
  u16*   hb1   = (u16*)  ((char*)d_ws + 100663296);      // 32MB  bf16 pong
  float* skipf = (float*)((char*)d_ws + 134217728);      // 4MB   [b][64][256]
  u16*   wT    = (u16*)  ((char*)d_ws + 138412032);      // 6MB
  u16*   swT   = (u16*)  ((char*)d_ws + 144703488);      // 2MB

  wprep<<<2048, 256, 0, stream>>>(conv_w, skip_w, wT, swT);
  hipMemsetAsync(skipf, 0, (size_t)BB * 64 * DHID * sizeof(float), stream);
  up_kernel<<<dim3(TT / 16, BB), 256, 0, stream>>>(X_lag, X_cov, up_w, up_b, hf, hb0);

  // minimal t-tiles per layer (receptive-field recurrence; also guarantees
  // layer i+1's halo reads stay within tiles layer i wrote to the pong buffer)
  static const int Ptab[NLAY] = {4, 5, 6, 7, 8, 9, 11, 15};
  u16* hin = hb0;
  u16* hout = hb1;
  for (int i = 0; i < NLAY; ++i) {
    const int ntiles = 16 - Ptab[i];
    layer_fused<<<dim3(ntiles, BB), 512, 0, stream>>>(
        hin, wT + (size_t)i * 3 * 512 * 256, conv_b + i * 512,
        swT + (size_t)i * 512 * 256, skip_b + i * 512,
        hf, hout, skipf, 1 << i, Ptab[i]);
    u16* tmp = hin; hin = hout; hout = tmp;
  }

  head_kernel<<<dim3(OSL, BB), 256, 0, stream>>>(
      skipf, fc_w, fc_b, loc_w, loc_b, sc_w, sc_b, (float*)d_out);
  loss_kernel<<<1, 256, 0, stream>>>(y, (float*)d_out);
}